// Round 14
// baseline (633.853 us; speedup 1.0000x reference)
//
#include <hip/hip_runtime.h>
#include <hip/hip_bf16.h>
#include <stdint.h>

#define NR 8192
#define FD 512
#define BM 64     // k_attn rows per band

typedef __attribute__((ext_vector_type(8))) short s8v;   // 8 bf16 (4 VGPRs) - MFMA A/B frag
typedef __attribute__((ext_vector_type(4))) float f32x4; // MFMA C/D frag

static __device__ __forceinline__ short bf16_rtne(float x) {
    union { float f; uint32_t u; } v; v.f = x;
    uint32_t r = (v.u + 0x7FFFu + ((v.u >> 16) & 1u)) >> 16;
    return (short)r;
}
static __device__ __forceinline__ float bf16_to_f32(short s) {
    union { uint32_t u; float f; } v; v.u = ((uint32_t)(uint16_t)s) << 16;
    return v.f;
}

// ---------------- K0: adj -> bitmask via ballot ----------------
__global__ void k_prepack(const int* __restrict__ adj,
                          unsigned long long* __restrict__ bm) {
    const int lane = threadIdx.x & 63;
    const int wv   = threadIdx.x >> 6;          // 4 waves/block
    const int gid  = blockIdx.x * 4 + wv;       // 32768 waves
    const int row  = gid >> 2;
    const int seg  = (gid & 3) * 2048;
    const int* p   = adj + (size_t)row * NR + seg + lane;
    unsigned long long* o = bm + (((size_t)row * NR + seg) >> 6);
#pragma unroll
    for (int g = 0; g < 8; ++g) {               // 8 groups of 256 j
        unsigned long long b0 = __ballot(p[g * 256]       != 0);
        unsigned long long b1 = __ballot(p[g * 256 + 64]  != 0);
        unsigned long long b2 = __ballot(p[g * 256 + 128] != 0);
        unsigned long long b3 = __ballot(p[g * 256 + 192] != 0);
        unsigned long long vs = (lane == 0) ? b0 : (lane == 1) ? b1
                              : (lane == 2) ? b2 : b3;
        if (lane < 4) o[g * 4 + lane] = vs;
    }
}

// ---------------- K0a: fp32 -> bf16 convert (inp) ----------------
__global__ void k_convert(const float* __restrict__ in, short* __restrict__ out) {
    int i = blockIdx.x * blockDim.x + threadIdx.x;   // one float4 per thread
    float4 v = ((const float4*)in)[i];
    short4 s;
    s.x = bf16_rtne(v.x); s.y = bf16_rtne(v.y);
    s.z = bf16_rtne(v.z); s.w = bf16_rtne(v.w);
    ((short4*)out)[i] = s;
}

// ---------------- K0b: W1 [k][n] -> W1T bf16 [n][k] ----------------
__global__ void k_w1t(const float* __restrict__ W1, short* __restrict__ W1T) {
    int i = blockIdx.x * 256 + threadIdx.x;  // 512*512
    int k = i & 511, n = i >> 9;
    W1T[(size_t)n * 512 + k] = bf16_rtne(W1[(size_t)k * 512 + n]);
}

// ---------------- K1: h = inp @ W1 + b1 ; writes h AND ht3 ----------------
// ht3 layout per 32-j tile jt: [wave=c/64][nt=(c%64)/16][qg=jrow/8][cm=c%16][jr=jrow%8]
// -> every k_attn B-frag load is a fully-coalesced lane-linear 1KB dwordx4.
__launch_bounds__(256)
__global__ void k_gemm_h(const short* __restrict__ A,   // inp bf16 [8192][512]
                         const short* __restrict__ BT,  // W1T bf16 [512][512]
                         const float* __restrict__ b1,
                         short* __restrict__ H,         // bf16 [8192][512]
                         short* __restrict__ HT3)       // bf16 [256][16384]
{
    const int lane = threadIdx.x & 63;
    const int wn   = threadIdx.x >> 6;     // 0..3
    const int m    = lane & 15;
    const int q    = lane >> 4;
    const int r0   = blockIdx.x * 32;
    const int c0   = blockIdx.y * 128 + wn * 32;

    f32x4 acc[2][2] = {};
#pragma unroll 1
    for (int k0 = 0; k0 < 512; k0 += 32) {
        s8v a[2], b[2];
#pragma unroll
        for (int rt = 0; rt < 2; ++rt)
            a[rt] = *(const s8v*)(A + (size_t)(r0 + rt * 16 + m) * 512 + k0 + q * 8);
#pragma unroll
        for (int nt = 0; nt < 2; ++nt)
            b[nt] = *(const s8v*)(BT + (size_t)(c0 + nt * 16 + m) * 512 + k0 + q * 8);
#pragma unroll
        for (int rt = 0; rt < 2; ++rt)
#pragma unroll
            for (int nt = 0; nt < 2; ++nt)
                acc[rt][nt] = __builtin_amdgcn_mfma_f32_16x16x32_bf16(a[rt], b[nt], acc[rt][nt], 0, 0, 0);
    }
    float b1v[2];
#pragma unroll
    for (int nt = 0; nt < 2; ++nt) b1v[nt] = b1[c0 + nt * 16 + m];

#pragma unroll
    for (int rt = 0; rt < 2; ++rt)
#pragma unroll
        for (int nt = 0; nt < 2; ++nt) {
            int col = c0 + nt * 16 + m;
            short4 hp;
#pragma unroll
            for (int r = 0; r < 4; ++r) {
                int row = r0 + rt * 16 + q * 4 + r;
                short hv = bf16_rtne(acc[rt][nt][r] + b1v[nt]);
                H[(size_t)row * 512 + col] = hv;
                ((short*)&hp)[r] = hv;
            }
            size_t off = (size_t)blockIdx.x * 16384
                       + (size_t)(blockIdx.y * 2 + (wn >> 1)) * 2048
                       + (size_t)((wn * 2 + nt) & 3) * 512
                       + (rt * 2 + (q >> 1)) * 128
                       + m * 8 + (q & 1) * 4;
            *(short4*)(HT3 + off) = hp;
        }
}

// ---------------- K3: f1 = h@a1, f2s = h@a2 + b2 ----------------
__global__ void k_f1f2(const short* __restrict__ H, const float* __restrict__ a1,
                       const float* __restrict__ a2, const float* __restrict__ b2,
                       float* __restrict__ f1, float* __restrict__ f2s)
{
    const int lane = threadIdx.x & 63;
    const int row  = blockIdx.x * 4 + (threadIdx.x >> 6);
    s8v hv = *(const s8v*)(H + (size_t)row * 512 + lane * 8);
    float4 a1l = ((const float4*)(a1 + lane * 8))[0];
    float4 a1h = ((const float4*)(a1 + lane * 8))[1];
    float4 a2l = ((const float4*)(a2 + lane * 8))[0];
    float4 a2h = ((const float4*)(a2 + lane * 8))[1];
    float hf[8];
#pragma unroll
    for (int i = 0; i < 8; ++i) hf[i] = bf16_to_f32(hv[i]);
    float s1 = hf[0] * a1l.x + hf[1] * a1l.y + hf[2] * a1l.z + hf[3] * a1l.w
             + hf[4] * a1h.x + hf[5] * a1h.y + hf[6] * a1h.z + hf[7] * a1h.w;
    float s2 = hf[0] * a2l.x + hf[1] * a2l.y + hf[2] * a2l.z + hf[3] * a2l.w
             + hf[4] * a2h.x + hf[5] * a2h.y + hf[6] * a2h.z + hf[7] * a2h.w;
#pragma unroll
    for (int o = 32; o > 0; o >>= 1) {
        s1 += __shfl_xor(s1, o);
        s2 += __shfl_xor(s2, o);
    }
    if (lane == 0) {
        f1[row]  = s1;
        f2s[row] = s2 + b2[0];
    }
}

// ---------------- K4: fused masked-softmax attention @ h (partials) --------
// grid 512 = 128 bands x 4 j-splits -> 2 blocks/CU, 4 waves/SIMD. 512 thr /
// 8 waves; wave tile 64r x 64c. B-frags register-prefetched depth-2 from ht3;
// weight tile in LDS dbuf, WGEN pieces in the MFMA shadow. WGEN unit inputs
// use a depth-2 ring: CONSUME (data staged 2 kts ago) strictly BEFORE STAGE
// in each iteration -- R13's stage-before-consume clobbered units 0/1.
__launch_bounds__(512, 4)
__global__ void k_attn(const uint32_t* __restrict__ bm, // [8192][256] bit j
                       const short* __restrict__ HT3,   // [256][16384]
                       const float* __restrict__ f1,
                       const float* __restrict__ f2s,
                       float* __restrict__ nump,        // [4][8192][512]
                       float* __restrict__ denomp)      // [4][8192]
{
    __shared__ __align__(16) short wt[2][BM * 256];     // 2 x 32 KB

    const int t    = threadIdx.x;
    const int lane = t & 63;
    const int w    = t >> 6;          // 0..7 col group (64 cols)
    const int m    = lane & 15;
    const int q    = lane >> 4;

    const int js   = blockIdx.x & 3;
    const int band = blockIdx.x >> 2; // 0..127
    const int r0   = band * BM;
    const int jb0  = js * 2048;
    const int jt0  = js * 64;         // first 32-j tile index

    const int prow = t >> 3;          // 0..63
    const int jg   = t & 7;

    const float f1v = f1[r0 + prow];
    const uint32_t* bmrow = bm + (size_t)(r0 + prow) * 256 + js * 64;
    const float* f2base = f2s + jb0;

    f32x4 acc[4][4] = {};
    float dsum = 0.f;

#define GAT_BLOAD(DST, KT)                                                     \
    {                                                                          \
        const short* s_ = HT3 + (size_t)(jt0 + (KT)) * 16384 + w * 2048        \
                        + q * 128 + m * 8;                                     \
        DST[0] = *(const s8v*)(s_);                                            \
        DST[1] = *(const s8v*)(s_ + 512);                                      \
        DST[2] = *(const s8v*)(s_ + 1024);                                     \
        DST[3] = *(const s8v*)(s_ + 1536);                                     \
    }

// one unit (8 weights) of row prow into wt[P]; BYTE = 8-bit mask, FA/FB float4
#define GAT_WUNIT(U, BYTE, FA, FB, P)                                          \
    {                                                                          \
        s8v wv_;                                                               \
        const float* ff_ = (const float*)&(FA);                                \
        _Pragma("unroll")                                                      \
        for (int jj = 0; jj < 4; ++jj) {                                       \
            float s_ = f1v + ff_[jj];                                          \
            float e_ = __expf(fmaxf(s_, 0.2f * s_));                           \
            float x_ = (((BYTE) >> jj) & 1u) ? e_ : 0.f;                       \
            dsum += x_; wv_[jj] = bf16_rtne(x_);                               \
        }                                                                      \
        const float* fg_ = (const float*)&(FB);                               \
        _Pragma("unroll")                                                      \
        for (int jj = 0; jj < 4; ++jj) {                                       \
            float s_ = f1v + fg_[jj];                                          \
            float e_ = __expf(fmaxf(s_, 0.2f * s_));                           \
            float x_ = (((BYTE) >> (4 + jj)) & 1u) ? e_ : 0.f;                 \
            dsum += x_; wv_[4 + jj] = bf16_rtne(x_);                           \
        }                                                                      \
        *(s8v*)&wt[P][prow * 256 + (((U) ^ (prow & 7)) << 3)] = wv_;           \
    }

    // prologue: full WGEN for chunk 0 -> wt[0]; preload B tiles 0 and 1
    {
#pragma unroll
        for (int k_ = 0; k_ < 4; ++k_) {
            const int u_ = jg + 8 * k_;
            uint32_t wd_ = bmrow[(jg >> 2) + 2 * k_];
            uint32_t byte_ = (wd_ >> ((jg & 3) * 8)) & 0xFFu;
            float4 fa_ = *(const float4*)(f2base + u_ * 8);
            float4 fb_ = *(const float4*)(f2base + u_ * 8 + 4);
            GAT_WUNIT(u_, byte_, fa_, fb_, 0)
        }
    }
    s8v breg[2][4];
    GAT_BLOAD(breg[0], 0)
    GAT_BLOAD(breg[1], 1)
    __syncthreads();

    uint32_t wu_mask[2];
    float4   wu_fa[2], wu_fb[2];

    int kt = 0;
#pragma unroll 1
    for (int ch = 0; ch < 8; ++ch) {          // 8 chunks x 256 j = 2048 j
        const int p = ch & 1;
#pragma unroll
        for (int kk = 0; kk < 8; ++kk, ++kt) {
            const int e = kk & 1;                // kt&1 == kk&1 (8 kts/chunk)
            // issue B loads for kt+2 (consumed 2 kts later; wraps to dummy)
            s8v bn[4];
            GAT_BLOAD(bn, (kt + 2) & 63)
            // A-frags from LDS weight tile
            s8v af[4];
#pragma unroll
            for (int i = 0; i < 4; ++i)
                af[i] = *(const s8v*)&wt[p][(i * 16 + m) * 256
                                            + (((kk * 4 + q) ^ (m & 7)) << 3)];
            // 16 MFMAs on current B regs
#pragma unroll
            for (int nt = 0; nt < 4; ++nt)
#pragma unroll
                for (int i = 0; i < 4; ++i)
                    acc[i][nt] = __builtin_amdgcn_mfma_f32_16x16x32_bf16(af[i], breg[e][nt], acc[i][nt], 0, 0, 0);
            // CONSUME: weight piece for next chunk (inputs staged 2 kts ago)
            if (kk >= 2 && kk <= 5 && ch < 7) {
                const int u_ = jg + 8 * (kk - 2);
                uint32_t byte_ = (wu_mask[e] >> ((jg & 3) * 8)) & 0xFFu;
                GAT_WUNIT(u_, byte_, wu_fa[e], wu_fb[e], p ^ 1)
            }
            // STAGE (after consume -- same slot, 2-kt distance): unit kk for kk+2
            if (kk < 4 && ch < 7) {
                const int k_ = kk;
                const int u_ = jg + 8 * k_;
                wu_mask[e] = bmrow[(ch + 1) * 8 + (jg >> 2) + 2 * k_];
                wu_fa[e] = *(const float4*)(f2base + (ch + 1) * 256 + u_ * 8);
                wu_fb[e] = *(const float4*)(f2base + (ch + 1) * 256 + u_ * 8 + 4);
            }
            // rotate B regs
#pragma unroll
            for (int nt = 0; nt < 4; ++nt) breg[e][nt] = bn[nt];
        }
        __syncthreads();
    }
#undef GAT_BLOAD
#undef GAT_WUNIT

    // ---- partial denominators: reduce over the 8 producer threads per row
    dsum += __shfl_xor(dsum, 1);
    dsum += __shfl_xor(dsum, 2);
    dsum += __shfl_xor(dsum, 4);
    if (jg == 0) denomp[(size_t)js * NR + r0 + prow] = dsum;

    // ---- partial numerators
    float* np = nump + (size_t)js * NR * FD;
#pragma unroll
    for (int i = 0; i < 4; ++i)
#pragma unroll
        for (int nt = 0; nt < 4; ++nt)
#pragma unroll
            for (int r = 0; r < 4; ++r) {
                int row = r0 + i * 16 + q * 4 + r;
                int col = w * 64 + nt * 16 + m;
                np[(size_t)row * FD + col] = acc[i][nt][r];
            }
}

// ---------------- K5: combine j-split partials, softmax divide, ELU --------
__global__ void k_combine(const float* __restrict__ nump,
                          const float* __restrict__ denomp,
                          float* __restrict__ out)
{
    size_t e = ((size_t)blockIdx.x * 256 + threadIdx.x) * 4;
    int row = (int)(e >> 9);
    float4 n0 = *(const float4*)(nump + e);
    float4 n1 = *(const float4*)(nump + (size_t)NR * FD + e);
    float4 n2 = *(const float4*)(nump + (size_t)2 * NR * FD + e);
    float4 n3 = *(const float4*)(nump + (size_t)3 * NR * FD + e);
    float d = denomp[row] + denomp[NR + row] + denomp[2 * NR + row] + denomp[3 * NR + row];
    float inv = 1.0f / d;
    float4 o;
    o.x = (n0.x + n1.x + n2.x + n3.x) * inv;
    o.y = (n0.y + n1.y + n2.y + n3.y) * inv;
    o.z = (n0.z + n1.z + n2.z + n3.z) * inv;
    o.w = (n0.w + n1.w + n2.w + n3.w) * inv;
    o.x = (o.x > 0.f) ? o.x : (__expf(o.x) - 1.f);
    o.y = (o.y > 0.f) ? o.y : (__expf(o.y) - 1.f);
    o.z = (o.z > 0.f) ? o.z : (__expf(o.z) - 1.f);
    o.w = (o.w > 0.f) ? o.w : (__expf(o.w) - 1.f);
    *(float4*)(out + e) = o;
}

extern "C" void kernel_launch(void* const* d_in, const int* in_sizes, int n_in,
                              void* d_out, int out_size, void* d_ws, size_t ws_size,
                              hipStream_t stream) {
    const float* inp = (const float*)d_in[0];
    const int*   adj = (const int*)d_in[1];
    const float* W1  = (const float*)d_in[2];
    const float* b1  = (const float*)d_in[3];
    const float* a1  = (const float*)d_in[4];
    const float* a2  = (const float*)d_in[5];
    const float* b2  = (const float*)d_in[6];
    float* out = (float*)d_out;

    // workspace layout
    short*    inp_bf = (short*)d_ws;                        // 8 MB
    short*    w1t    = inp_bf + (size_t)NR * FD;            // 0.5 MB
    short*    h      = w1t + (size_t)FD * FD;               // 8 MB
    short*    ht3    = h + (size_t)NR * FD;                 // 8 MB
    uint32_t* bmw    = (uint32_t*)(ht3 + (size_t)FD * NR);  // 8 MB
    float*    f1     = (float*)(bmw + (size_t)NR * 256);    // 32 KB
    float*    f2s    = f1 + NR;                             // 32 KB
    float*    nump   = f2s + NR;                            // 64 MB
    float*    denomp = nump + (size_t)4 * NR * FD;          // 128 KB

    k_prepack<<<NR, 256, 0, stream>>>(adj, (unsigned long long*)bmw);
    k_convert<<<(NR * FD / 4) / 256, 256, 0, stream>>>(inp, inp_bf);
    k_w1t<<<(FD * FD) / 256, 256, 0, stream>>>(W1, w1t);
    dim3 g1(NR / 32, FD / 128);
    k_gemm_h<<<g1, 256, 0, stream>>>(inp_bf, w1t, b1, h, ht3);
    k_f1f2<<<NR / 4, 256, 0, stream>>>(h, a1, a2, b2, f1, f2s);
    k_attn<<<128 * 4, 512, 0, stream>>>(bmw, ht3, f1, f2s, nump, denomp);
    k_combine<<<(NR * FD / 4) / 256, 256, 0, stream>>>(nump, denomp, out);
}

// Round 15
// 513.813 us; speedup vs baseline: 1.2336x; 1.2336x over previous
//
#include <hip/hip_runtime.h>
#include <hip/hip_bf16.h>
#include <stdint.h>

#define NR 8192
#define FD 512
#define BM 64     // k_attn rows per band

typedef __attribute__((ext_vector_type(8))) short s8v;   // 8 bf16 (4 VGPRs) - MFMA A/B frag
typedef __attribute__((ext_vector_type(4))) float f32x4; // MFMA C/D frag

static __device__ __forceinline__ short bf16_rtne(float x) {
    union { float f; uint32_t u; } v; v.f = x;
    uint32_t r = (v.u + 0x7FFFu + ((v.u >> 16) & 1u)) >> 16;
    return (short)r;
}
static __device__ __forceinline__ float bf16_to_f32(short s) {
    union { uint32_t u; float f; } v; v.u = ((uint32_t)(uint16_t)s) << 16;
    return v.f;
}

// ---------------- K0: adj -> bitmask via ballot ----------------
__global__ void k_prepack(const int* __restrict__ adj,
                          unsigned long long* __restrict__ bm) {
    const int lane = threadIdx.x & 63;
    const int wv   = threadIdx.x >> 6;          // 4 waves/block
    const int gid  = blockIdx.x * 4 + wv;       // 32768 waves
    const int row  = gid >> 2;
    const int seg  = (gid & 3) * 2048;
    const int* p   = adj + (size_t)row * NR + seg + lane;
    unsigned long long* o = bm + (((size_t)row * NR + seg) >> 6);
#pragma unroll
    for (int g = 0; g < 8; ++g) {               // 8 groups of 256 j
        unsigned long long b0 = __ballot(p[g * 256]       != 0);
        unsigned long long b1 = __ballot(p[g * 256 + 64]  != 0);
        unsigned long long b2 = __ballot(p[g * 256 + 128] != 0);
        unsigned long long b3 = __ballot(p[g * 256 + 192] != 0);
        unsigned long long vs = (lane == 0) ? b0 : (lane == 1) ? b1
                              : (lane == 2) ? b2 : b3;
        if (lane < 4) o[g * 4 + lane] = vs;
    }
}

// ---------------- K0a: fp32 -> bf16 convert (inp) ----------------
__global__ void k_convert(const float* __restrict__ in, short* __restrict__ out) {
    int i = blockIdx.x * blockDim.x + threadIdx.x;   // one float4 per thread
    float4 v = ((const float4*)in)[i];
    short4 s;
    s.x = bf16_rtne(v.x); s.y = bf16_rtne(v.y);
    s.z = bf16_rtne(v.z); s.w = bf16_rtne(v.w);
    ((short4*)out)[i] = s;
}

// ---------------- K0b: W1 [k][n] -> W1T bf16 [n][k] ----------------
__global__ void k_w1t(const float* __restrict__ W1, short* __restrict__ W1T) {
    int i = blockIdx.x * 256 + threadIdx.x;  // 512*512
    int k = i & 511, n = i >> 9;
    W1T[(size_t)n * 512 + k] = bf16_rtne(W1[(size_t)k * 512 + n]);
}

// ---------------- K1: h = inp @ W1 + b1 ; writes h AND ht3 ----------------
// ht3 layout per 32-j tile jt: [grp=c/64][sub=(c%64)/16][qg=jrow/8][cm=c%16][jr=jrow%8]
// -> every k_attn B-frag load is a fully-coalesced lane-linear 1KB dwordx4.
__launch_bounds__(256)
__global__ void k_gemm_h(const short* __restrict__ A,   // inp bf16 [8192][512]
                         const short* __restrict__ BT,  // W1T bf16 [512][512]
                         const float* __restrict__ b1,
                         short* __restrict__ H,         // bf16 [8192][512]
                         short* __restrict__ HT3)       // bf16 [256][16384]
{
    const int lane = threadIdx.x & 63;
    const int wn   = threadIdx.x >> 6;     // 0..3
    const int m    = lane & 15;
    const int q    = lane >> 4;
    const int r0   = blockIdx.x * 32;
    const int c0   = blockIdx.y * 128 + wn * 32;

    f32x4 acc[2][2] = {};
#pragma unroll 1
    for (int k0 = 0; k0 < 512; k0 += 32) {
        s8v a[2], b[2];
#pragma unroll
        for (int rt = 0; rt < 2; ++rt)
            a[rt] = *(const s8v*)(A + (size_t)(r0 + rt * 16 + m) * 512 + k0 + q * 8);
#pragma unroll
        for (int nt = 0; nt < 2; ++nt)
            b[nt] = *(const s8v*)(BT + (size_t)(c0 + nt * 16 + m) * 512 + k0 + q * 8);
#pragma unroll
        for (int rt = 0; rt < 2; ++rt)
#pragma unroll
            for (int nt = 0; nt < 2; ++nt)
                acc[rt][nt] = __builtin_amdgcn_mfma_f32_16x16x32_bf16(a[rt], b[nt], acc[rt][nt], 0, 0, 0);
    }
    float b1v[2];
#pragma unroll
    for (int nt = 0; nt < 2; ++nt) b1v[nt] = b1[c0 + nt * 16 + m];

#pragma unroll
    for (int rt = 0; rt < 2; ++rt)
#pragma unroll
        for (int nt = 0; nt < 2; ++nt) {
            int col = c0 + nt * 16 + m;
            short4 hp;
#pragma unroll
            for (int r = 0; r < 4; ++r) {
                int row = r0 + rt * 16 + q * 4 + r;
                short hv = bf16_rtne(acc[rt][nt][r] + b1v[nt]);
                H[(size_t)row * 512 + col] = hv;
                ((short*)&hp)[r] = hv;
            }
            size_t off = (size_t)blockIdx.x * 16384
                       + (size_t)(blockIdx.y * 2 + (wn >> 1)) * 2048
                       + (size_t)((wn * 2 + nt) & 3) * 512
                       + (rt * 2 + (q >> 1)) * 128
                       + m * 8 + (q & 1) * 4;
            *(short4*)(HT3 + off) = hp;
        }
}

// ---------------- K3: f1 = h@a1, f2s = h@a2 + b2 ----------------
__global__ void k_f1f2(const short* __restrict__ H, const float* __restrict__ a1,
                       const float* __restrict__ a2, const float* __restrict__ b2,
                       float* __restrict__ f1, float* __restrict__ f2s)
{
    const int lane = threadIdx.x & 63;
    const int row  = blockIdx.x * 4 + (threadIdx.x >> 6);
    s8v hv = *(const s8v*)(H + (size_t)row * 512 + lane * 8);
    float4 a1l = ((const float4*)(a1 + lane * 8))[0];
    float4 a1h = ((const float4*)(a1 + lane * 8))[1];
    float4 a2l = ((const float4*)(a2 + lane * 8))[0];
    float4 a2h = ((const float4*)(a2 + lane * 8))[1];
    float hf[8];
#pragma unroll
    for (int i = 0; i < 8; ++i) hf[i] = bf16_to_f32(hv[i]);
    float s1 = hf[0] * a1l.x + hf[1] * a1l.y + hf[2] * a1l.z + hf[3] * a1l.w
             + hf[4] * a1h.x + hf[5] * a1h.y + hf[6] * a1h.z + hf[7] * a1h.w;
    float s2 = hf[0] * a2l.x + hf[1] * a2l.y + hf[2] * a2l.z + hf[3] * a2l.w
             + hf[4] * a2h.x + hf[5] * a2h.y + hf[6] * a2h.z + hf[7] * a2h.w;
#pragma unroll
    for (int o = 32; o > 0; o >>= 1) {
        s1 += __shfl_xor(s1, o);
        s2 += __shfl_xor(s2, o);
    }
    if (lane == 0) {
        f1[row]  = s1;
        f2s[row] = s2 + b2[0];
    }
}

// ---------------- K4: fused masked-softmax attention @ h (partials) --------
// grid 512 = 128 bands x 2 cb (256-col halves) x 2 js (4096-j halves).
// 512 thr / 8 waves; wave tile 64r x 32c -> acc[4][2]=32 AGPR, total regs ~95
// -> fits the 128 cap of __launch_bounds__(512,4): 2 blocks/CU, 4 waves/SIMD
// WITHOUT spilling (R14's 64x64 tile spilled ~500MB of scratch to HBM).
// cb pair recomputes the same weight tile (x2 WGEN, ~9us total) - the price
// for doubled TLP. B-frags register-prefetched depth-2 from ht3; WGEN pieces
// in MFMA shadow; wu ring is consume-before-stage.
__launch_bounds__(512, 4)
__global__ void k_attn(const uint32_t* __restrict__ bm, // [8192][256] bit j
                       const short* __restrict__ HT3,   // [256][16384]
                       const float* __restrict__ f1,
                       const float* __restrict__ f2s,
                       float* __restrict__ nump,        // [2][8192][512]
                       float* __restrict__ denomp)      // [2][8192]
{
    __shared__ __align__(16) short wt[2][BM * 256];     // 2 x 32 KB

    const int t    = threadIdx.x;
    const int lane = t & 63;
    const int w    = t >> 6;          // 0..7 col group (32 cols)
    const int m    = lane & 15;
    const int q    = lane >> 4;

    const int js   = blockIdx.x & 1;
    const int cb   = (blockIdx.x >> 1) & 1;
    const int band = blockIdx.x >> 2; // 0..127
    const int r0   = band * BM;
    const int jb0  = js * 4096;
    const int jt0  = js * 128;        // first 32-j tile index (128 tiles/js)

    const int prow = t >> 3;          // 0..63
    const int jg   = t & 7;

    const float f1v = f1[r0 + prow];
    const uint32_t* bmrow = bm + (size_t)(r0 + prow) * 256 + js * 128;
    const float* f2base = f2s + jb0;

    // ht3 base for this wave's 32 cols: grp = cb*4 + (w>>1), sub = (w&1)*2
    const int gbase = (cb * 4 + (w >> 1)) * 2048 + (w & 1) * 1024 + q * 128 + m * 8;

    f32x4 acc[4][2] = {};
    float dsum = 0.f;

#define GAT_BLOAD(DST, KT)                                                     \
    {                                                                          \
        const short* s_ = HT3 + (size_t)(jt0 + (KT)) * 16384 + gbase;          \
        DST[0] = *(const s8v*)(s_);                                            \
        DST[1] = *(const s8v*)(s_ + 512);                                      \
    }

// one unit (8 weights) of row prow into wt[P]; BYTE = 8-bit mask, FA/FB float4
#define GAT_WUNIT(U, BYTE, FA, FB, P)                                          \
    {                                                                          \
        s8v wv_;                                                               \
        const float* ff_ = (const float*)&(FA);                                \
        _Pragma("unroll")                                                      \
        for (int jj = 0; jj < 4; ++jj) {                                       \
            float s_ = f1v + ff_[jj];                                          \
            float e_ = __expf(fmaxf(s_, 0.2f * s_));                           \
            float x_ = (((BYTE) >> jj) & 1u) ? e_ : 0.f;                       \
            dsum += x_; wv_[jj] = bf16_rtne(x_);                               \
        }                                                                      \
        const float* fg_ = (const float*)&(FB);                               \
        _Pragma("unroll")                                                      \
        for (int jj = 0; jj < 4; ++jj) {                                       \
            float s_ = f1v + fg_[jj];                                          \
            float e_ = __expf(fmaxf(s_, 0.2f * s_));                           \
            float x_ = (((BYTE) >> (4 + jj)) & 1u) ? e_ : 0.f;                 \
            dsum += x_; wv_[4 + jj] = bf16_rtne(x_);                           \
        }                                                                      \
        *(s8v*)&wt[P][prow * 256 + (((U) ^ (prow & 7)) << 3)] = wv_;           \
    }

    // prologue: full WGEN for chunk 0 -> wt[0]; preload B tiles 0 and 1
    {
#pragma unroll
        for (int k_ = 0; k_ < 4; ++k_) {
            const int u_ = jg + 8 * k_;
            uint32_t wd_ = bmrow[(jg >> 2) + 2 * k_];
            uint32_t byte_ = (wd_ >> ((jg & 3) * 8)) & 0xFFu;
            float4 fa_ = *(const float4*)(f2base + u_ * 8);
            float4 fb_ = *(const float4*)(f2base + u_ * 8 + 4);
            GAT_WUNIT(u_, byte_, fa_, fb_, 0)
        }
    }
    s8v breg[2][2];
    GAT_BLOAD(breg[0], 0)
    GAT_BLOAD(breg[1], 1)
    __syncthreads();

    uint32_t wu_mask[2];
    float4   wu_fa[2], wu_fb[2];

    int kt = 0;
#pragma unroll 1
    for (int ch = 0; ch < 16; ++ch) {         // 16 chunks x 256 j = 4096 j
        const int p = ch & 1;
#pragma unroll
        for (int kk = 0; kk < 8; ++kk, ++kt) {
            const int e = kk & 1;                // kt&1 == kk&1 (8 kts/chunk)
            // issue B loads for kt+2 (consumed 2 kts later; wraps to dummy)
            s8v bn[2];
            GAT_BLOAD(bn, (kt + 2) & 127)
            // A-frags from LDS weight tile
            s8v af[4];
#pragma unroll
            for (int i = 0; i < 4; ++i)
                af[i] = *(const s8v*)&wt[p][(i * 16 + m) * 256
                                            + (((kk * 4 + q) ^ (m & 7)) << 3)];
            // 8 MFMAs on current B regs
#pragma unroll
            for (int nt = 0; nt < 2; ++nt)
#pragma unroll
                for (int i = 0; i < 4; ++i)
                    acc[i][nt] = __builtin_amdgcn_mfma_f32_16x16x32_bf16(af[i], breg[e][nt], acc[i][nt], 0, 0, 0);
            // CONSUME: weight piece for next chunk (inputs staged 2 kts ago)
            if (kk >= 2 && kk <= 5 && ch < 15) {
                const int u_ = jg + 8 * (kk - 2);
                uint32_t byte_ = (wu_mask[e] >> ((jg & 3) * 8)) & 0xFFu;
                GAT_WUNIT(u_, byte_, wu_fa[e], wu_fb[e], p ^ 1)
            }
            // STAGE (after consume -- same slot, 2-kt distance): unit kk for kk+2
            if (kk < 4 && ch < 15) {
                const int k_ = kk;
                const int u_ = jg + 8 * k_;
                wu_mask[e] = bmrow[(ch + 1) * 8 + (jg >> 2) + 2 * k_];
                wu_fa[e] = *(const float4*)(f2base + (ch + 1) * 256 + u_ * 8);
                wu_fb[e] = *(const float4*)(f2base + (ch + 1) * 256 + u_ * 8 + 4);
            }
            // rotate B regs
#pragma unroll
            for (int nt = 0; nt < 2; ++nt) breg[e][nt] = bn[nt];
        }
        __syncthreads();
    }
#undef GAT_BLOAD
#undef GAT_WUNIT

    // ---- partial denominators (cb blocks duplicate WGEN; cb==0 writes)
    dsum += __shfl_xor(dsum, 1);
    dsum += __shfl_xor(dsum, 2);
    dsum += __shfl_xor(dsum, 4);
    if (cb == 0 && jg == 0) denomp[(size_t)js * NR + r0 + prow] = dsum;

    // ---- partial numerators
    float* np = nump + (size_t)js * NR * FD;
#pragma unroll
    for (int i = 0; i < 4; ++i)
#pragma unroll
        for (int nt = 0; nt < 2; ++nt)
#pragma unroll
            for (int r = 0; r < 4; ++r) {
                int row = r0 + i * 16 + q * 4 + r;
                int col = cb * 256 + w * 32 + nt * 16 + m;
                np[(size_t)row * FD + col] = acc[i][nt][r];
            }
}

// ---------------- K5: combine j-split partials, softmax divide, ELU --------
__global__ void k_combine(const float* __restrict__ nump,
                          const float* __restrict__ denomp,
                          float* __restrict__ out)
{
    size_t e = ((size_t)blockIdx.x * 256 + threadIdx.x) * 4;
    int row = (int)(e >> 9);
    float4 n0 = *(const float4*)(nump + e);
    float4 n1 = *(const float4*)(nump + (size_t)NR * FD + e);
    float d = denomp[row] + denomp[NR + row];
    float inv = 1.0f / d;
    float4 o;
    o.x = (n0.x + n1.x) * inv;
    o.y = (n0.y + n1.y) * inv;
    o.z = (n0.z + n1.z) * inv;
    o.w = (n0.w + n1.w) * inv;
    o.x = (o.x > 0.f) ? o.x : (__expf(o.x) - 1.f);
    o.y = (o.y > 0.f) ? o.y : (__expf(o.y) - 1.f);
    o.z = (o.z > 0.f) ? o.z : (__expf(o.z) - 1.f);
    o.w = (o.w > 0.f) ? o.w : (__expf(o.w) - 1.f);
    *(float4*)(out + e) = o;
}

extern "C" void kernel_launch(void* const* d_in, const int* in_sizes, int n_in,
                              void* d_out, int out_size, void* d_ws, size_t ws_size,
                              hipStream_t stream) {
    const float* inp = (const float*)d_in[0];
    const int*   adj = (const int*)d_in[1];
    const float* W1  = (const float*)d_in[2];
    const float* b1  = (const float*)d_in[3];
    const float* a1  = (const float*)d_in[4];
    const float* a2  = (const float*)d_in[5];
    const float* b2  = (const float*)d_in[6];
    float* out = (float*)d_out;

    // workspace layout
    short*    inp_bf = (short*)d_ws;                        // 8 MB
    short*    w1t    = inp_bf + (size_t)NR * FD;            // 0.5 MB
    short*    h      = w1t + (size_t)FD * FD;               // 8 MB
    short*    ht3    = h + (size_t)NR * FD;                 // 8 MB
    uint32_t* bmw    = (uint32_t*)(ht3 + (size_t)FD * NR);  // 8 MB
    float*    f1     = (float*)(bmw + (size_t)NR * 256);    // 32 KB
    float*    f2s    = f1 + NR;                             // 32 KB
    float*    nump   = f2s + NR;                            // 32 MB
    float*    denomp = nump + (size_t)2 * NR * FD;          // 64 KB

    k_prepack<<<NR, 256, 0, stream>>>(adj, (unsigned long long*)bmw);
    k_convert<<<(NR * FD / 4) / 256, 256, 0, stream>>>(inp, inp_bf);
    k_w1t<<<(FD * FD) / 256, 256, 0, stream>>>(W1, w1t);
    dim3 g1(NR / 32, FD / 128);
    k_gemm_h<<<g1, 256, 0, stream>>>(inp_bf, w1t, b1, h, ht3);
    k_f1f2<<<NR / 4, 256, 0, stream>>>(h, a1, a2, b2, f1, f2s);
    k_attn<<<128 * 2 * 2, 512, 0, stream>>>(bmw, ht3, f1, f2s, nump, denomp);
    k_combine<<<(NR * FD / 4) / 256, 256, 0, stream>>>(nump, denomp, out);
}